// Round 4
// baseline (218.174 us; speedup 1.0000x reference)
//
#include <hip/hip_runtime.h>

// Blockwise 16x16 2D DCT (out = K @ T @ K^T), fp32, memory-bound.
// BARRIER-FREE: each wave is an independent double-buffered pipeline over
// 16x64 strips (4 tiles). global_load_lds -> per-wave LDS region; wave-internal
// counted vmcnt keeps prefetch in flight; in-order LDS (per-wave) replaces
// __syncthreads. 768 blocks x 256 thr (4 waves), 3 blocks/CU = 12 indep waves/CU.

#define IMG_W 1024
#define WLDS  3136      // floats per wave: 2*1024 (in dbuf) + 1088 (U / stage)
#define UOFFW 2048

__device__ __forceinline__ void gload_lds16(const float* gp, float* lp) {
    // async 16B/lane global->LDS; LDS dest = wave-uniform base + lane*16
    __builtin_amdgcn_global_load_lds(
        (const __attribute__((address_space(1))) void*)gp,
        (__attribute__((address_space(3))) void*)lp,
        16, 0, 0);
}

__global__ __launch_bounds__(256, 3) void dct16_kernel(
    const float* __restrict__ x,
    const float* __restrict__ kern,      // 16x16 DCT matrix, row-major
    float* __restrict__ out,
    int strips_per_wave, int total_strips)
{
    __shared__ float lds[4 * WLDS];      // 50176 B -> 3 blocks/CU

    const int tid  = threadIdx.x;
    const int lane = tid & 63;
    const int wid  = tid >> 6;
    float* wlds = &lds[wid * WLDS];

    const int gw = blockIdx.x * 4 + wid;           // global wave id
    int s0 = gw * strips_per_wave;
    if (s0 >= total_strips) return;                // no barriers -> safe
    int ns = strips_per_wave;
    if (s0 + ns > total_strips) ns = total_strips - s0;

    const int lr = lane >> 4;                      // 0..3
    const int lc = lane & 15;                      // 0..15

    // strip s: 16 rows x 64 cols. band = s>>4, col-16th = s&15.
    auto sbase = [](int s) -> size_t {
        return (size_t)(s >> 4) * (16 * IMG_W) + (size_t)(s & 15) * 64;
    };

    // 4 DMA instrs: chunk i = rows 4i..4i+3; lane l -> row 4i+(l>>4), col (l&15)*4.
    // LDS linear: float idx = i*256 + l*4  (== i*256 + (l>>4)*64 + (l&15)*4).
    auto dma_strip = [&](int s, int b) {
        const float* g = x + sbase(s) + (size_t)lr * IMG_W + lc * 4;
        float* l = wlds + b * 1024;
        #pragma unroll
        for (int i = 0; i < 4; ++i)
            gload_lds16(g + (size_t)(4 * i) * IMG_W, l + i * 256);
    };

    dma_strip(s0, 0);    // prologue: 4 vm-ops in flight

    for (int k = 0; k < ns; ++k) {
        const int cur = k & 1;
        if (k + 1 < ns) dma_strip(s0 + k + 1, cur ^ 1);

        // Per-wave vm queue (issue order): DMA_k(4), stores_{k-1}(4), DMA_{k+1}(4).
        // Wait only for DMA_k; stores + next prefetch stay in flight.
        if (k == 0) {
            if (ns > 1) { asm volatile("s_waitcnt vmcnt(4)" ::: "memory"); }
            else        { asm volatile("s_waitcnt vmcnt(0)" ::: "memory"); }
        } else if (k + 1 < ns) {
            asm volatile("s_waitcnt vmcnt(8)" ::: "memory");
        } else {
            asm volatile("s_waitcnt vmcnt(4)" ::: "memory");
        }

        const float* ibuf = wlds + cur * 1024;

        // ---- Pass 1: U = K @ T. Lane = one of 64 columns. ----
        float tv[16];
        #pragma unroll
        for (int i = 0; i < 4; ++i)
            #pragma unroll
            for (int jr = 0; jr < 4; ++jr)
                tv[i * 4 + jr] = ibuf[i * 256 + jr * 64 + lane];   // row 4i+jr

        float u[16];
        #pragma unroll
        for (int i = 0; i < 16; ++i) u[i] = 0.0f;
        #pragma unroll
        for (int j = 0; j < 16; ++j) {
            float tj = tv[j];
            #pragma unroll
            for (int i = 0; i < 16; ++i)
                u[i] = fmaf(kern[i * 16 + j], tj, u[i]);   // uniform -> s_load
        }

        // U row-major, stride 68 (272B: 16B-aligned, breaks pow2 banks)
        float* U = wlds + UOFFW;
        #pragma unroll
        for (int i = 0; i < 16; ++i)
            U[i * 68 + lane] = u[i];
        // same-wave LDS ops are in-order: pass-2 reads see these writes.

        // ---- Pass 2: out = U @ K^T. Lane = (tile lr, row lc). ----
        float ur[16];
        #pragma unroll
        for (int p = 0; p < 4; ++p) {
            float4 v = *reinterpret_cast<const float4*>(&U[lc * 68 + lr * 16 + p * 4]);
            ur[p*4+0] = v.x; ur[p*4+1] = v.y; ur[p*4+2] = v.z; ur[p*4+3] = v.w;
        }

        float o[16];
        #pragma unroll
        for (int m = 0; m < 16; ++m) {
            float acc = 0.0f;
            #pragma unroll
            for (int l = 0; l < 16; ++l)
                acc = fmaf(ur[l], kern[m * 16 + l], acc);
            o[m] = acc;
        }

        // ---- Stage into U region (dead after ur reads), stride-260 chunks ----
        // lane (t=lr, r=lc): row r cols [t*16, t*16+16) -> chunk r>>2, offset
        // (r&3)*64 + t*16. 260-stride keeps b128 writes conflict-free.
        #pragma unroll
        for (int f = 0; f < 4; ++f)
            *reinterpret_cast<float4*>(&U[(lc >> 2) * 260 + (lc & 3) * 64 + lr * 16 + f * 4]) =
                make_float4(o[f*4+0], o[f*4+1], o[f*4+2], o[f*4+3]);

        // ---- Store: 4 x 1KB wave-contiguous float4 runs ----
        {
            float* g = out + sbase(s0 + k) + (size_t)lr * IMG_W + lc * 4;
            #pragma unroll
            for (int i = 0; i < 4; ++i) {
                float4 v = *reinterpret_cast<const float4*>(&U[i * 260 + lane * 4]);
                *reinterpret_cast<float4*>(g + (size_t)(4 * i) * IMG_W) = v;
            }
        }
        // next iter's pass-1 U writes are same-wave in-order after these reads;
        // next DMA targets the other in-buffer, whose reads completed last iter.
    }
}

extern "C" void kernel_launch(void* const* d_in, const int* in_sizes, int n_in,
                              void* d_out, int out_size, void* d_ws, size_t ws_size,
                              hipStream_t stream) {
    const float* x    = (const float*)d_in[0];
    const float* kern = (const float*)d_in[1];
    float* out        = (float*)d_out;

    const int n_img        = in_sizes[0] / (IMG_W * IMG_W);   // 96
    const int total_strips = n_img * 64 * 16;                 // 98304 strips of 16x64
    const int n_waves      = 768 * 4;                         // 3072 waves
    const int per_wave     = (total_strips + n_waves - 1) / n_waves;   // 32

    dct16_kernel<<<768, 256, 0, stream>>>(x, kern, out, per_wave, total_strips);
}